// Round 2
// baseline (2337.605 us; speedup 1.0000x reference)
//
#include <hip/hip_runtime.h>

#define TT 2000
#define NB 100
#define N1 100
#define KIN 784
#define JW 8

// ---------- fast math (v_rcp_f32 ~1 ulp; 138x accuracy headroom measured R0) ----------
__device__ __forceinline__ float rcp_f(float d) { return __builtin_amdgcn_rcpf(d); }
__device__ __forceinline__ float sigmoid3(float V) {
  // sigmoid((V-20)/3) = 1/(1+exp((20-V)/3))
  return rcp_f(1.0f + __expf((20.0f - V) * (1.0f / 3.0f)));
}
__device__ __forceinline__ float gate_u(float a, float b, float p) {
  float s = 0.005f * (a + b);
  return (a * 0.01f + (1.0f - s) * p) * rcp_f(s + 1.0f);
}
__device__ __forceinline__ void hh_step(float& V, float& m, float& n, float& h,
                                        float& y, float zk) {
  float p1 = 40.0f * m * m * m * h;
  float nn2 = n * n;
  float p2 = 35.0f * nn2 * nn2;
  float Gs = 0.005f * (p1 + p2 + 0.3f + 0.04f * y);
  float E = p1 * 55.0f + p2 * (-77.0f) + (0.3f * (-65.0f));
  float Vn = (V * (1.0f - Gs) + 0.01f * (E + 1.5f)) * rcp_f(1.0f + Gs);

  float eN  = __expf((25.0f - Vn) * (1.0f / 9.0f));
  float eBN = __expf((Vn - 25.0f) * (1.0f / 9.0f));
  float eM  = __expf((-Vn - 35.0f) * (1.0f / 9.0f));
  float eBM = __expf((Vn + 35.0f) * (1.0f / 9.0f));
  float aH  = 0.25f * __expf((-Vn - 90.0f) * (1.0f / 12.0f));
  float bH  = 0.25f * __expf((Vn + 34.0f) * (1.0f / 12.0f));
  float dN = 1.0f - eN, dBN = 1.0f - eBN, dM = 1.0f - eM, dBM = 1.0f - eBM;
  float aN = (dN  == 0.0f) ? 0.18f  :  0.02f  * (Vn - 25.0f) * rcp_f(dN);
  float bN = (dBN == 0.0f) ? 0.018f : -0.002f * (Vn - 25.0f) * rcp_f(dBN);
  float aM = (dM  == 0.0f) ? 1.638f :  0.182f * (Vn + 35.0f) * rcp_f(dM);
  float bM = (dBM == 0.0f) ? 1.116f : -0.124f * (Vn + 35.0f) * rcp_f(dBM);

  m = gate_u(aM, bM, m);
  n = gate_u(aN, bN, n);
  h = gate_u(aH, bH, h);
  y = gate_u(zk, 0.1f, y);
  V = Vn;
}

// ---------- GEMM body: z^T[b][c][tt] = sum_k batch[b][t0+tt][k] * W1[c][k] ----------
// 128-row x 100-col tile, K-tile 16, 256 threads, thread = 2 rows x 25 cols.
__device__ void gemm_body(const float* __restrict__ batch, const float* __restrict__ W1,
                          float* __restrict__ zT, int t0, int Ct, int gb) {
  __shared__ float As[16][128];
  __shared__ float Bs[100][16];
  const int tid = threadIdx.x;
  const int r = tid & 63;
  const int g = tid >> 6;
  const int c0 = g * 25;
  const int row0 = gb * 128;
  const int M = NB * Ct;

  int fr0 = row0 + (tid >> 2);
  int fr1 = fr0 + 64;
  int cr0 = fr0 < M ? fr0 : (M - 1);
  int cr1 = fr1 < M ? fr1 : (M - 1);
  const float* srcA0 = batch + ((size_t)(cr0 / Ct) * TT + t0 + (cr0 % Ct)) * KIN + (tid & 3) * 4;
  const float* srcA1 = batch + ((size_t)(cr1 / Ct) * TT + t0 + (cr1 % Ct)) * KIN + (tid & 3) * 4;
  const float* srcB0 = W1 + (size_t)(tid >> 2) * KIN + (tid & 3) * 4;
  const bool hasB1 = (tid < 144);
  const float* srcB1 = W1 + (size_t)((tid >> 2) + 64) * KIN + (tid & 3) * 4;

  float acc[50];
#pragma unroll
  for (int i = 0; i < 50; ++i) acc[i] = 0.0f;

  for (int kt = 0; kt < KIN; kt += 16) {
    float4 a0 = *(const float4*)(srcA0 + kt);
    float4 a1 = *(const float4*)(srcA1 + kt);
    float4 b0 = *(const float4*)(srcB0 + kt);
    float4 b1 = make_float4(0.f, 0.f, 0.f, 0.f);
    if (hasB1) b1 = *(const float4*)(srcB1 + kt);
    __syncthreads();
    {
      int kq4 = (tid & 3) * 4;
      int wr = tid >> 2;
      As[kq4 + 0][wr] = a0.x; As[kq4 + 1][wr] = a0.y;
      As[kq4 + 2][wr] = a0.z; As[kq4 + 3][wr] = a0.w;
      As[kq4 + 0][wr + 64] = a1.x; As[kq4 + 1][wr + 64] = a1.y;
      As[kq4 + 2][wr + 64] = a1.z; As[kq4 + 3][wr + 64] = a1.w;
      *(float4*)&Bs[wr][kq4] = b0;
      if (hasB1) *(float4*)&Bs[wr + 64][kq4] = b1;
    }
    __syncthreads();
#pragma unroll
    for (int kk = 0; kk < 16; kk += 4) {
      float a0r[4], a1r[4];
#pragma unroll
      for (int i = 0; i < 4; ++i) { a0r[i] = As[kk + i][r]; a1r[i] = As[kk + i][r + 64]; }
#pragma unroll
      for (int j = 0; j < 25; ++j) {
        float4 bv = *(const float4*)&Bs[c0 + j][kk];
        acc[j]      += a0r[0] * bv.x; acc[j]      += a0r[1] * bv.y;
        acc[j]      += a0r[2] * bv.z; acc[j]      += a0r[3] * bv.w;
        acc[25 + j] += a1r[0] * bv.x; acc[25 + j] += a1r[1] * bv.y;
        acc[25 + j] += a1r[2] * bv.z; acc[25 + j] += a1r[3] * bv.w;
      }
    }
  }
  // transposed store: z^T[b][c][tt], lane-coalesced per j
  int rg0 = row0 + r, rg1 = rg0 + 64;
  if (rg0 < M) {
    int b0 = rg0 / Ct, tt0 = rg0 % Ct;
    float* dst = zT + ((size_t)b0 * 100 + c0) * Ct + tt0;
#pragma unroll
    for (int j = 0; j < 25; ++j) dst[(size_t)j * Ct] = acc[j];
  }
  if (rg1 < M) {
    int b1i = rg1 / Ct, tt1 = rg1 % Ct;
    float* dst = zT + ((size_t)b1i * 100 + c0) * Ct + tt1;
#pragma unroll
    for (int j = 0; j < 25; ++j) dst[(size_t)j * Ct] = acc[25 + j];
  }
}

// ---------- scan body: windows of JW steps, one barrier per window ----------
// waves 0-1 lanes (tid<100): layer-1 neurons. wave 2 tid 128..167: layer-2
// (4 lanes per output). 3*JW-row LDS ring; L2 lags L1 by one window.
__device__ void scan_body(const float* __restrict__ zT, const float* __restrict__ W2,
                          float* __restrict__ out, float* __restrict__ st,
                          int t0, int Ct) {
  __shared__ float ring[3 * JW][100];
  const int b = blockIdx.x;
  const int tid = threadIdx.x;

  float* SV1 = st;         float* SM1 = st + 10000;
  float* SN1 = st + 20000; float* SH1 = st + 30000;
  float* SY1 = st + 40000; float* SV2 = st + 50000;
  float* SM2 = st + 51000; float* SN2 = st + 52000;
  float* SH2 = st + 53000; float* SY2 = st + 54000;
  float* ST1 = st + 55000;

  const bool isL1 = (tid < N1);
  float V1 = 0, m1 = 0, n1 = 0, h1 = 0, y1 = 0, T1v = 0;
  const float* zrow = nullptr;
  float zc[JW];
  const bool ctAligned = ((Ct & 3) == 0);
  if (isL1) {
    int ix = b * N1 + tid;
    if (t0 == 0) { V1 = -70.f; m1 = 0; n1 = 0; h1 = 1.f; y1 = 0.f; T1v = sigmoid3(-70.f); }
    else { V1 = SV1[ix]; m1 = SM1[ix]; n1 = SN1[ix]; h1 = SH1[ix]; y1 = SY1[ix]; T1v = ST1[ix]; }
    ring[0][tid] = T1v;
    zrow = zT + ((size_t)b * 100 + tid) * Ct;
    if (ctAligned && JW <= Ct) {
      float4 v0 = *(const float4*)(zrow);
      float4 v1 = *(const float4*)(zrow + 4);
      zc[0] = v0.x; zc[1] = v0.y; zc[2] = v0.z; zc[3] = v0.w;
      zc[4] = v1.x; zc[5] = v1.y; zc[6] = v1.z; zc[7] = v1.w;
    } else {
#pragma unroll
      for (int j = 0; j < JW; ++j) zc[j] = (1 + j <= Ct) ? zrow[j] : 0.f;
    }
  }
  float V2 = 0, m2 = 0, n2 = 0, h2 = 0, y2 = 0;
  float w2r[25];
  int o = 0, jj = 0;
  const bool l2 = (tid >= 128 && tid < 168);
  if (l2) {
    int u = tid - 128; o = u >> 2; jj = u & 3;
#pragma unroll
    for (int i = 0; i < 25; ++i) w2r[i] = W2[o * 100 + jj * 25 + i];
    if (t0 == 0) {
      V2 = -70.f; m2 = 0; n2 = 0; h2 = 1.f; y2 = 1.f;
      if (jj == 0) out[(size_t)b * TT * 10 + o] = sigmoid3(-70.f);
    } else {
      int ix = b * 10 + o;
      V2 = SV2[ix]; m2 = SM2[ix]; n2 = SN2[ix]; h2 = SH2[ix]; y2 = SY2[ix];
    }
  }
  __syncthreads();

  const int NW = (Ct + JW - 1) / JW;
  for (int w = 0; w <= NW; ++w) {
    if (isL1 && w < NW) {
      // prefetch z for window w+1 (hidden under this window's chain)
      float zn[JW];
      int sbase = (w + 1) * JW;  // z rows sbase..sbase+7 drive steps sbase+1..sbase+8
      if (ctAligned && sbase + JW <= Ct) {
        float4 v0 = *(const float4*)(zrow + sbase);
        float4 v1 = *(const float4*)(zrow + sbase + 4);
        zn[0] = v0.x; zn[1] = v0.y; zn[2] = v0.z; zn[3] = v0.w;
        zn[4] = v1.x; zn[5] = v1.y; zn[6] = v1.z; zn[7] = v1.w;
      } else {
#pragma unroll
        for (int j = 0; j < JW; ++j)
          zn[j] = (sbase + 1 + j <= Ct) ? zrow[sbase + j] : 0.f;
      }
      int rw = (w * JW + 1) % (3 * JW);
#pragma unroll
      for (int j = 0; j < JW; ++j) {
        int s = w * JW + 1 + j;
        if (s <= Ct) {
          hh_step(V1, m1, n1, h1, y1, zc[j]);
          T1v = sigmoid3(V1);
          int rr = rw + j; if (rr >= 3 * JW) rr -= 3 * JW;
          ring[rr][tid] = T1v;
        }
      }
#pragma unroll
      for (int j = 0; j < JW; ++j) zc[j] = zn[j];
    }
    if (l2 && w >= 1) {
      int rbase = ((w - 1) * JW) % (3 * JW);   // in {0, 8, 16}; rbase+j <= 23, no wrap
#pragma unroll
      for (int j = 0; j < JW; ++j) {
        int s = (w - 1) * JW + 1 + j;
        if (s <= Ct) {
          const float* tp = &ring[rbase + j][jj * 25];
          float s0 = 0, s1 = 0, s2 = 0, s3 = 0;
#pragma unroll
          for (int i = 0; i < 6; ++i) {
            s0 += tp[i]      * w2r[i];
            s1 += tp[6 + i]  * w2r[6 + i];
            s2 += tp[12 + i] * w2r[12 + i];
            s3 += tp[18 + i] * w2r[18 + i];
          }
          s3 += tp[24] * w2r[24];
          float sv = (s0 + s1) + (s2 + s3);
          sv += __shfl_xor(sv, 1);
          sv += __shfl_xor(sv, 2);
          hh_step(V2, m2, n2, h2, y2, sv);
          if (jj == 0) out[((size_t)b * TT + (t0 + s)) * 10 + o] = sigmoid3(V2);
        }
      }
    }
    asm volatile("s_waitcnt lgkmcnt(0)\n\ts_barrier" ::: "memory");
  }

  if (isL1) {
    int ix = b * N1 + tid;
    SV1[ix] = V1; SM1[ix] = m1; SN1[ix] = n1; SH1[ix] = h1; SY1[ix] = y1; ST1[ix] = T1v;
  }
  if (l2 && jj == 0) {
    int ix = b * 10 + o;
    SV2[ix] = V2; SM2[ix] = m2; SN2[ix] = n2; SH2[ix] = h2; SY2[ix] = y2;
  }
}

// ---------- fused dispatch: blocks [0,nScan) scan chunk d-1; rest GEMM chunk d ----------
__global__ __launch_bounds__(256) void fused_hh(
    const float* __restrict__ batch, const float* __restrict__ W1,
    const float* __restrict__ W2, float* __restrict__ out, float* __restrict__ st,
    const float* __restrict__ z_scan, float* __restrict__ z_gemm,
    int sc_t0, int sc_Ct, int gm_t0, int gm_Ct, int nScan) {
  if ((int)blockIdx.x < nScan) {
    scan_body(z_scan, W2, out, st, sc_t0, sc_Ct);
  } else {
    gemm_body(batch, W1, z_gemm, gm_t0, gm_Ct, (int)blockIdx.x - nScan);
  }
}

extern "C" void kernel_launch(void* const* d_in, const int* in_sizes, int n_in,
                              void* d_out, int out_size, void* d_ws, size_t ws_size,
                              hipStream_t stream) {
  (void)in_sizes; (void)n_in; (void)out_size;
  const float* batch = (const float*)d_in[0];
  const float* W1 = (const float*)d_in[1];
  const float* W2 = (const float*)d_in[2];
  float* out = (float*)d_out;

  // workspace: 2 z buffers (double-buffered chunks) + 65000-float state
  const size_t stateBytes = 65000u * 4u;
  size_t avail = (ws_size > stateBytes + 1024) ? (ws_size - stateBytes - 1024) : 0;
  long long cm = (long long)(avail / 80000ull);   // 2 * 100*100*4 bytes per z-row
  int C = (int)(cm > 200 ? 200 : cm);
  if (C < 8) C = 8;
  C &= ~3;                                        // multiple of 4 for float4 z loads

  // chunk table: small first chunk to shrink the pipeline-fill bubble
  int cs[300], ct[300];
  int nc = 0, pos = 0;
  int cf = (C < 96) ? C : 96;
  cs[nc] = 0; ct[nc] = cf; pos = cf; ++nc;
  while (pos < TT - 1) {
    int c = (TT - 1) - pos;
    if (c > C) c = C;
    cs[nc] = pos; ct[nc] = c; ++nc; pos += c;
  }

  float* zb0 = (float*)d_ws;
  float* zb1 = zb0 + (size_t)C * 10000;
  float* st  = zb1 + (size_t)C * 10000;

  for (int d = 0; d <= nc; ++d) {
    int nScan = (d >= 1) ? NB : 0;
    int gmCt = (d < nc) ? ct[d] : 0;
    int gmT0 = (d < nc) ? cs[d] : 0;
    int scCt = (d >= 1) ? ct[d - 1] : 0;
    int scT0 = (d >= 1) ? cs[d - 1] : 0;
    int gblocks = (gmCt > 0) ? (NB * gmCt + 127) / 128 : 0;
    int grid = nScan + gblocks;
    if (grid == 0) continue;
    const float* zs = ((d - 1) & 1) ? zb1 : zb0;
    float* zg = (d & 1) ? zb1 : zb0;
    fused_hh<<<dim3((unsigned)grid), dim3(256), 0, stream>>>(
        batch, W1, W2, out, st, zs, zg, scT0, scCt, gmT0, gmCt, nScan);
  }
}

// Round 3
// 1553.133 us; speedup vs baseline: 1.5051x; 1.5051x over previous
//
#include <hip/hip_runtime.h>

#define TT 2000
#define NB 100
#define N1 100
#define KIN 784
#define JW 8          // steps per window (one barrier per window)
#define RING 24       // 3 windows; slot = step mod 24 -> disjoint W/R per iter

// ---------- fast math (v_rcp_f32 ~1 ulp; 138x accuracy headroom measured) ----------
__device__ __forceinline__ float rcp_f(float d) { return __builtin_amdgcn_rcpf(d); }
__device__ __forceinline__ float sigmoid3(float V) {
  return rcp_f(1.0f + __expf((20.0f - V) * (1.0f / 3.0f)));
}
__device__ __forceinline__ float gate_u(float a, float b, float p) {
  float s = 0.005f * (a + b);
  return (a * 0.01f + (1.0f - s) * p) * rcp_f(s + 1.0f);
}
__device__ __forceinline__ void hh_step(float& V, float& m, float& n, float& h,
                                        float& y, float zk) {
  float p1 = 40.0f * m * m * m * h;
  float nn2 = n * n;
  float p2 = 35.0f * nn2 * nn2;
  float Gs = 0.005f * (p1 + p2 + 0.3f + 0.04f * y);
  float E = p1 * 55.0f + p2 * (-77.0f) + (0.3f * (-65.0f));
  float Vn = (V * (1.0f - Gs) + 0.01f * (E + 1.5f)) * rcp_f(1.0f + Gs);

  float eN  = __expf((25.0f - Vn) * (1.0f / 9.0f));
  float eBN = __expf((Vn - 25.0f) * (1.0f / 9.0f));
  float eM  = __expf((-Vn - 35.0f) * (1.0f / 9.0f));
  float eBM = __expf((Vn + 35.0f) * (1.0f / 9.0f));
  float aH  = 0.25f * __expf((-Vn - 90.0f) * (1.0f / 12.0f));
  float bH  = 0.25f * __expf((Vn + 34.0f) * (1.0f / 12.0f));
  float dN = 1.0f - eN, dBN = 1.0f - eBN, dM = 1.0f - eM, dBM = 1.0f - eBM;
  float aN = (dN  == 0.0f) ? 0.18f  :  0.02f  * (Vn - 25.0f) * rcp_f(dN);
  float bN = (dBN == 0.0f) ? 0.018f : -0.002f * (Vn - 25.0f) * rcp_f(dBN);
  float aM = (dM  == 0.0f) ? 1.638f :  0.182f * (Vn + 35.0f) * rcp_f(dM);
  float bM = (dBM == 0.0f) ? 1.116f : -0.124f * (Vn + 35.0f) * rcp_f(dBM);

  m = gate_u(aM, bM, m);
  n = gate_u(aN, bN, n);
  h = gate_u(aH, bH, h);
  y = gate_u(zk, 0.1f, y);
  V = Vn;
}

// ---------- GEMM (unchanged from R1, proven ~530us): z1[b*Ct+tt][c] ----------
__global__ __launch_bounds__(256) void gemm_z1(const float* __restrict__ batch,
                                               const float* __restrict__ W1,
                                               float* __restrict__ z1,
                                               int t0, int Ct, int M) {
  __shared__ float As[16][128];
  __shared__ float Bs[100][16];
  const int tid = threadIdx.x;
  const int r = tid & 63;
  const int g = tid >> 6;
  const int c0 = g * 25;
  const int row0 = blockIdx.x * 128;

  int fr0 = row0 + (tid >> 2);
  int fr1 = fr0 + 64;
  int cr0 = fr0 < M ? fr0 : (M - 1);
  int cr1 = fr1 < M ? fr1 : (M - 1);
  const float* srcA0 = batch + ((size_t)(cr0 / Ct) * TT + t0 + (cr0 % Ct)) * KIN + (tid & 3) * 4;
  const float* srcA1 = batch + ((size_t)(cr1 / Ct) * TT + t0 + (cr1 % Ct)) * KIN + (tid & 3) * 4;
  const float* srcB0 = W1 + (size_t)(tid >> 2) * KIN + (tid & 3) * 4;
  const bool hasB1 = (tid < 144);
  const float* srcB1 = W1 + (size_t)((tid >> 2) + 64) * KIN + (tid & 3) * 4;

  float acc[50];
#pragma unroll
  for (int i = 0; i < 50; ++i) acc[i] = 0.0f;

  for (int kt = 0; kt < KIN; kt += 16) {
    float4 a0 = *(const float4*)(srcA0 + kt);
    float4 a1 = *(const float4*)(srcA1 + kt);
    float4 b0 = *(const float4*)(srcB0 + kt);
    float4 b1 = make_float4(0.f, 0.f, 0.f, 0.f);
    if (hasB1) b1 = *(const float4*)(srcB1 + kt);
    __syncthreads();
    {
      int kq4 = (tid & 3) * 4;
      int wr = tid >> 2;
      As[kq4 + 0][wr] = a0.x; As[kq4 + 1][wr] = a0.y;
      As[kq4 + 2][wr] = a0.z; As[kq4 + 3][wr] = a0.w;
      As[kq4 + 0][wr + 64] = a1.x; As[kq4 + 1][wr + 64] = a1.y;
      As[kq4 + 2][wr + 64] = a1.z; As[kq4 + 3][wr + 64] = a1.w;
      *(float4*)&Bs[wr][kq4] = b0;
      if (hasB1) *(float4*)&Bs[wr + 64][kq4] = b1;
    }
    __syncthreads();
#pragma unroll
    for (int kk = 0; kk < 16; kk += 4) {
      float a0r[4], a1r[4];
#pragma unroll
      for (int i = 0; i < 4; ++i) { a0r[i] = As[kk + i][r]; a1r[i] = As[kk + i][r + 64]; }
#pragma unroll
      for (int j = 0; j < 25; ++j) {
        float4 bv = *(const float4*)&Bs[c0 + j][kk];
        acc[j]      += a0r[0] * bv.x; acc[j]      += a0r[1] * bv.y;
        acc[j]      += a0r[2] * bv.z; acc[j]      += a0r[3] * bv.w;
        acc[25 + j] += a1r[0] * bv.x; acc[25 + j] += a1r[1] * bv.y;
        acc[25 + j] += a1r[2] * bv.z; acc[25 + j] += a1r[3] * bv.w;
      }
    }
  }
  int rg0 = row0 + r, rg1 = row0 + r + 64;
  if (rg0 < M) {
    float* dst = z1 + (size_t)rg0 * 100 + c0;
#pragma unroll
    for (int j = 0; j < 25; ++j) dst[j] = acc[j];
  }
  if (rg1 < M) {
    float* dst = z1 + (size_t)rg1 * 100 + c0;
#pragma unroll
    for (int j = 0; j < 25; ++j) dst[j] = acc[25 + j];
  }
}

// ---------- windowed two-layer scan: one barrier per JW steps ----------
// 192 threads = 3 waves. tid<100 (waves 0-1): layer-1 neurons. wave 2
// (tid 128..167): layer-2, 4 lanes per output (o=(u>>2), jj=u&3).
// T1 ring: slot s%24 holds "T1 after step s". Iter w: L1 writes slots
// w*8+1..w*8+8 (mod 24), L2 reads slots (w-1)*8..(w-1)*8+7 (mod 24) --
// always disjoint; one lgkmcnt-only barrier per iter keeps stores/prefetch
// in flight.
__global__ __launch_bounds__(192) void hh_scan(const float* __restrict__ z1buf,
                                               const float* __restrict__ W2,
                                               float* __restrict__ out,
                                               float* __restrict__ st,
                                               int t0, int Ct) {
  __shared__ float ring[RING][100];
  const int b = blockIdx.x;
  const int tid = threadIdx.x;

  float* SV1 = st;         float* SM1 = st + 10000;
  float* SN1 = st + 20000; float* SH1 = st + 30000;
  float* SY1 = st + 40000; float* SV2 = st + 50000;
  float* SM2 = st + 51000; float* SN2 = st + 52000;
  float* SH2 = st + 53000; float* SY2 = st + 54000;
  float* ST1 = st + 55000;

  const bool isL1 = (tid < N1);
  float V1 = 0, m1 = 0, n1 = 0, h1 = 0, y1 = 0, T1v = 0;
  const float* zrow = nullptr;
  float zc[JW];
  if (isL1) {
    int ix = b * N1 + tid;
    if (t0 == 0) { V1 = -70.f; m1 = 0; n1 = 0; h1 = 1.f; y1 = 0.f; T1v = sigmoid3(-70.f); }
    else { V1 = SV1[ix]; m1 = SM1[ix]; n1 = SN1[ix]; h1 = SH1[ix]; y1 = SY1[ix]; T1v = ST1[ix]; }
    ring[0][tid] = T1v;
    zrow = z1buf + (size_t)b * Ct * 100 + tid;
#pragma unroll
    for (int j = 0; j < JW; ++j) zc[j] = (j < Ct) ? zrow[(size_t)j * 100] : 0.f;
  }

  // layer-2 weights as float4 chunks: lane (o,jj) owns cols 16q+4jj..+3,
  // q=0..5; jj==0 also owns the 96..99 tail. (28 weight regs max)
  float V2 = 0, m2 = 0, n2 = 0, h2 = 0, y2 = 0;
  float4 w2q[6]; float4 w2t = make_float4(0, 0, 0, 0);
  int o = 0, jj = 0;
  const bool l2 = (tid >= 128 && tid < 168);
  if (l2) {
    int u = tid - 128; o = u >> 2; jj = u & 3;
#pragma unroll
    for (int q = 0; q < 6; ++q)
      w2q[q] = *(const float4*)(W2 + o * 100 + q * 16 + jj * 4);
    if (jj == 0) w2t = *(const float4*)(W2 + o * 100 + 96);
    if (t0 == 0) {
      V2 = -70.f; m2 = 0; n2 = 0; h2 = 1.f; y2 = 1.f;
      out[(size_t)b * TT * 10 + o] = (jj == 0) ? sigmoid3(-70.f) : out[(size_t)b * TT * 10 + o];
      if (jj != 0) { /* no store */ }
    } else {
      int ix = b * 10 + o;
      V2 = SV2[ix]; m2 = SM2[ix]; n2 = SN2[ix]; h2 = SH2[ix]; y2 = SY2[ix];
    }
  }
  __syncthreads();

  const int NW = (Ct + JW - 1) / JW;
  for (int w = 0; w <= NW; ++w) {
    if (isL1 && w < NW) {
      // prefetch next window's z (coalesced: 100 lanes x consecutive floats)
      float zn[JW];
      int nb = (w + 1) * JW;
#pragma unroll
      for (int j = 0; j < JW; ++j)
        zn[j] = (nb + j < Ct) ? zrow[(size_t)(nb + j) * 100] : 0.f;

      int base1 = (w * JW) % RING;
#pragma unroll
      for (int j = 0; j < JW; ++j) {
        int s = w * JW + 1 + j;
        if (s <= Ct) {
          hh_step(V1, m1, n1, h1, y1, zc[j]);
          T1v = sigmoid3(V1);
          int rr = base1 + 1 + j; if (rr >= RING) rr -= RING;
          ring[rr][tid] = T1v;
        }
      }
#pragma unroll
      for (int j = 0; j < JW; ++j) zc[j] = zn[j];
    }
    if (l2 && w >= 1) {
      int rbase = ((w - 1) * JW) % RING;   // {0,8,16}; rbase+7 <= 23, no wrap
      // hoist all 8 dot products (independent; float4 LDS reads, broadcast
      // across the 10 o-groups, conflict-free) ahead of the serial hh chain
      float sv[JW];
#pragma unroll
      for (int j = 0; j < JW; ++j) {
        const float* rp = ring[rbase + j];
        float a0 = 0, a1 = 0;
#pragma unroll
        for (int q = 0; q < 6; q += 2) {
          float4 v0 = *(const float4*)(rp + q * 16 + jj * 4);
          float4 v1 = *(const float4*)(rp + (q + 1) * 16 + jj * 4);
          a0 += v0.x * w2q[q].x + v0.y * w2q[q].y + v0.z * w2q[q].z + v0.w * w2q[q].w;
          a1 += v1.x * w2q[q + 1].x + v1.y * w2q[q + 1].y + v1.z * w2q[q + 1].z + v1.w * w2q[q + 1].w;
        }
        float acc = a0 + a1;
        if (jj == 0) {
          float4 vt = *(const float4*)(rp + 96);
          acc += vt.x * w2t.x + vt.y * w2t.y + vt.z * w2t.z + vt.w * w2t.w;
        }
        sv[j] = acc;
      }
#pragma unroll
      for (int j = 0; j < JW; ++j) {
        sv[j] += __shfl_xor(sv[j], 1);
        sv[j] += __shfl_xor(sv[j], 2);
      }
#pragma unroll
      for (int j = 0; j < JW; ++j) {
        int s = (w - 1) * JW + 1 + j;
        if (s <= Ct) {
          hh_step(V2, m2, n2, h2, y2, sv[j]);
          if (jj == 0) out[((size_t)b * TT + (t0 + s)) * 10 + o] = sigmoid3(V2);
        }
      }
    }
    asm volatile("s_waitcnt lgkmcnt(0)\n\ts_barrier" ::: "memory");
  }

  if (isL1) {
    int ix = b * N1 + tid;
    SV1[ix] = V1; SM1[ix] = m1; SN1[ix] = n1; SH1[ix] = h1; SY1[ix] = y1; ST1[ix] = T1v;
  }
  if (l2 && jj == 0) {
    int ix = b * 10 + o;
    SV2[ix] = V2; SM2[ix] = m2; SN2[ix] = n2; SH2[ix] = h2; SY2[ix] = y2;
  }
}

extern "C" void kernel_launch(void* const* d_in, const int* in_sizes, int n_in,
                              void* d_out, int out_size, void* d_ws, size_t ws_size,
                              hipStream_t stream) {
  (void)in_sizes; (void)n_in; (void)out_size;
  const float* batch = (const float*)d_in[0];
  const float* W1 = (const float*)d_in[1];
  const float* W2 = (const float*)d_in[2];
  float* out = (float*)d_out;

  const size_t stateBytes = 65000u * 4u;
  size_t avail = (ws_size > stateBytes + 4096) ? (ws_size - stateBytes - 4096) : 0;
  long long Cll = (long long)(avail / 40000ull);   // bytes per z row (100x100x4)
  int C = (int)(Cll > 1999 ? 1999 : Cll);
  if (C < 1) C = 1;

  float* z1buf = (float*)d_ws;
  size_t zbytes = (((size_t)C * 40000) + 255) & ~(size_t)255;
  float* st = (float*)((char*)d_ws + zbytes);

  for (int t0 = 0; t0 < TT - 1; t0 += C) {
    int Ct = (TT - 1) - t0;
    if (Ct > C) Ct = C;
    int M = NB * Ct;
    dim3 gg((unsigned)((M + 127) / 128));
    gemm_z1<<<gg, dim3(256), 0, stream>>>(batch, W1, z1buf, t0, Ct, M);
    hh_scan<<<dim3(NB), dim3(192), 0, stream>>>(z1buf, W2, out, st, t0, Ct);
  }
}